// Round 2
// baseline (663.938 us; speedup 1.0000x reference)
//
#include <hip/hip_runtime.h>
#include <hip/hip_bf16.h>

typedef unsigned short u16;
typedef unsigned int   u32;

#define N_NODES 50000
#define N_EDGES 500000
#define IN_DIM  512
#define HID     256
#define OUT_DIM 64

typedef __bf16 bf16x8 __attribute__((ext_vector_type(8)));
typedef float  f32x4  __attribute__((ext_vector_type(4)));

__device__ __forceinline__ float bf2f(u16 u) {
  union { u32 i; float f; } x; x.i = ((u32)u) << 16; return x.f;
}
__device__ __forceinline__ u16 f2bf(float f) {
  union { float f; u32 i; } x; x.f = f;
  u32 r = x.i + 0x7FFFu + ((x.i >> 16) & 1u);
  return (u16)(r >> 16);
}

// ---------------- dtype detector ----------------
// If the float-tensor buffers actually hold packed bf16, the LOW 16 bits of
// each 32-bit word are a bf16 normal sample -> exponent field ((w>>7)&0xFF)
// concentrated near 127. If they hold f32, those bits are random mantissa
// bits -> ~16% land in the window. Count over 1024 words.
__global__ void detect_dtype(const u32* __restrict__ feat, int* __restrict__ flag) {
  __shared__ int s[256];
  int t = threadIdx.x;
  int hits = 0;
  for (int i = t; i < 1024; i += 256) {
    u32 e = (feat[i] >> 7) & 0xFF;
    hits += (e >= 100 && e <= 140) ? 1 : 0;
  }
  s[t] = hits;
  __syncthreads();
  for (int o = 128; o > 0; o >>= 1) {
    if (t < o) s[t] += s[t + o];
    __syncthreads();
  }
  if (t == 0) *flag = (s[0] > 716) ? 1 : 0;  // 1 = bf16, 0 = f32
}

// ---------------- canonicalize input to bf16 ----------------
__global__ void cvt_to_bf16(const void* __restrict__ src, u16* __restrict__ dst,
                            int n, const int* __restrict__ flag) {
  int i = blockIdx.x * 256 + threadIdx.x;
  if (i >= n) return;
  if (*flag)
    dst[i] = ((const u16*)src)[i];
  else
    dst[i] = f2bf(((const float*)src)[i]);
}

// ---------------- transpose (tiny matrices) ----------------
__global__ void transpose_bf16(const u16* __restrict__ src, u16* __restrict__ dst,
                               int R, int C) {
  int i = blockIdx.x * 256 + threadIdx.x;
  if (i < R * C) {
    int r = i / C, c = i - r * C;
    dst[c * R + r] = src[i];
  }
}

// ---------------- NT GEMM: C[M,N] = A[M,K] * B[N,K]^T, bf16 in, fp32 acc ----
// MODE 0: write f32 to Cf (workspace intermediate)
// MODE 1: write final output (f32 or bf16 per *flag) at outbase+out_off
// MODE 2: MODE 1 + also write bf16 copy to Cb (feeds next GEMM)
template <int MODE>
__global__ __launch_bounds__(256) void gemm_nt(const u16* __restrict__ A,
                                               const u16* __restrict__ B,
                                               float* __restrict__ Cf,
                                               void* __restrict__ outbase,
                                               size_t out_off,
                                               u16* __restrict__ Cb,
                                               const int* __restrict__ flag,
                                               int M, int N, int K) {
  __shared__ __bf16 As[64 * 48];  // row stride 48 elems = 96 B (16B-aligned)
  __shared__ __bf16 Bs[64 * 48];

  const int tid  = threadIdx.x;
  const int m0   = blockIdx.x * 64;
  const int n0   = blockIdx.y * 64;
  const int wave = tid >> 6;
  const int lane = tid & 63;
  const int wm   = (wave >> 1) * 32;
  const int wn   = (wave & 1) * 32;
  const int quad = lane >> 4;
  const int l16  = lane & 15;

  const int srow = tid >> 2;
  const int sseg = (tid & 3) * 8;
  int arow = m0 + srow;
  if (arow >= M) arow = M - 1;  // clamp; C stores are row-guarded
  const size_t a_base = (size_t)arow * K + sseg;
  const size_t b_base = (size_t)(n0 + srow) * K + sseg;

  f32x4 acc[2][2];
#pragma unroll
  for (int i = 0; i < 2; ++i)
#pragma unroll
    for (int j = 0; j < 2; ++j) acc[i][j] = (f32x4)0.f;

  for (int k0 = 0; k0 < K; k0 += 32) {
    uint4 av = *(const uint4*)(A + a_base + k0);
    uint4 bv = *(const uint4*)(B + b_base + k0);
    __syncthreads();
    *(uint4*)(&As[srow * 48 + sseg]) = av;
    *(uint4*)(&Bs[srow * 48 + sseg]) = bv;
    __syncthreads();

    bf16x8 af[2], bfr[2];
#pragma unroll
    for (int mi = 0; mi < 2; ++mi)
      af[mi] = *(const bf16x8*)(&As[(wm + mi * 16 + l16) * 48 + quad * 8]);
#pragma unroll
    for (int ni = 0; ni < 2; ++ni)
      bfr[ni] = *(const bf16x8*)(&Bs[(wn + ni * 16 + l16) * 48 + quad * 8]);
#pragma unroll
    for (int mi = 0; mi < 2; ++mi)
#pragma unroll
      for (int ni = 0; ni < 2; ++ni)
        acc[mi][ni] = __builtin_amdgcn_mfma_f32_16x16x32_bf16(
            af[mi], bfr[ni], acc[mi][ni], 0, 0, 0);
  }

  const int out_bf = (MODE != 0) ? *flag : 0;
#pragma unroll
  for (int mi = 0; mi < 2; ++mi)
#pragma unroll
    for (int ni = 0; ni < 2; ++ni)
#pragma unroll
      for (int r = 0; r < 4; ++r) {
        int gr = m0 + wm + mi * 16 + quad * 4 + r;  // row = quad*4+reg
        int gc = n0 + wn + ni * 16 + l16;           // col = lane&15
        if (gr < M) {
          float  v   = acc[mi][ni][r];
          size_t idx = (size_t)gr * N + gc;
          if (MODE == 0) {
            Cf[idx] = v;
          } else {
            if (out_bf) ((u16*)outbase)[out_off + idx] = f2bf(v);
            else        ((float*)outbase)[out_off + idx] = v;
            if (MODE == 2) Cb[idx] = f2bf(v);
          }
        }
      }
}

// ---------------- node attention dots ----------------
__global__ __launch_bounds__(256) void attn_dots(const float* __restrict__ h1p,
                                                 const u16* __restrict__ atts,
                                                 const u16* __restrict__ attd,
                                                 float* __restrict__ a_s,
                                                 float* __restrict__ a_d) {
  __shared__ __align__(16) float ss[HID];
  __shared__ __align__(16) float sd[HID];
  int t = threadIdx.x;
  ss[t] = bf2f(atts[t]);
  sd[t] = bf2f(attd[t]);
  __syncthreads();
  int row  = blockIdx.x * 4 + (t >> 6);
  int lane = t & 63;
  float4 h = *((const float4*)(h1p + (size_t)row * HID) + lane);
  float4 s = *((const float4*)ss + lane);
  float4 d = *((const float4*)sd + lane);
  float vs = h.x * s.x + h.y * s.y + h.z * s.z + h.w * s.w;
  float vd = h.x * d.x + h.y * d.y + h.z * d.z + h.w * d.w;
#pragma unroll
  for (int off = 32; off > 0; off >>= 1) {
    vs += __shfl_down(vs, off);
    vd += __shfl_down(vd, off);
  }
  if (lane == 0) {
    a_s[row] = vs;
    a_d[row] = vd;
  }
}

// ---------------- CSR build ----------------
__global__ void hist_kernel(const int* __restrict__ dst, int* __restrict__ counts) {
  int e = blockIdx.x * 256 + threadIdx.x;
  if (e < N_EDGES) atomicAdd(&counts[dst[e]], 1);
}

__global__ void block_sum(const int* __restrict__ counts, int n,
                          int* __restrict__ bsums) {
  __shared__ int s[256];
  int i = blockIdx.x * 256 + threadIdx.x;
  s[threadIdx.x] = (i < n) ? counts[i] : 0;
  __syncthreads();
  for (int off = 128; off > 0; off >>= 1) {
    if (threadIdx.x < off) s[threadIdx.x] += s[threadIdx.x + off];
    __syncthreads();
  }
  if (threadIdx.x == 0) bsums[blockIdx.x] = s[0];
}

__global__ void scan_bsums(const int* __restrict__ bsums, int nb,
                           int* __restrict__ boffs) {
  __shared__ int s[256];
  int t = threadIdx.x;
  int v = (t < nb) ? bsums[t] : 0;
  s[t] = v;
  __syncthreads();
  for (int off = 1; off < 256; off <<= 1) {
    int add = (t >= off) ? s[t - off] : 0;
    __syncthreads();
    s[t] += add;
    __syncthreads();
  }
  boffs[t] = s[t] - v;  // exclusive
}

__global__ void scan_final(const int* __restrict__ counts,
                           const int* __restrict__ boffs, int n,
                           int* __restrict__ offsets, int* __restrict__ cursor) {
  __shared__ int s[256];
  int t = threadIdx.x;
  int i = blockIdx.x * 256 + t;
  int v = (i < n) ? counts[i] : 0;
  s[t] = v;
  __syncthreads();
  for (int off = 1; off < 256; off <<= 1) {
    int add = (t >= off) ? s[t - off] : 0;
    __syncthreads();
    s[t] += add;
    __syncthreads();
  }
  int excl = boffs[blockIdx.x] + s[t] - v;
  if (i < n) {
    offsets[i] = excl;
    cursor[i]  = excl;
  }
  if (i == n - 1) offsets[n] = excl + v;
}

// a = sigmoid(.) in (0,1) -> exp never overflows; the segment-max shift
// cancels algebraically in softmax, so it is skipped (rounding-level diff).
__global__ void edge_scatter(const int* __restrict__ src, const int* __restrict__ dst,
                             const float* __restrict__ a_s, const float* __restrict__ a_d,
                             float* __restrict__ denom, int* __restrict__ cursor,
                             int* __restrict__ csr_src, float* __restrict__ csr_e) {
  int e = blockIdx.x * 256 + threadIdx.x;
  if (e >= N_EDGES) return;
  int s = src[e], d = dst[e];
  float x  = a_s[s] + a_d[d];
  float a  = 1.f / (1.f + expf(-x));  // sigmoid
  float ev = expf(a);
  atomicAdd(&denom[d], ev);
  int pos = atomicAdd(&cursor[d], 1);
  csr_src[pos] = s;
  csr_e[pos]   = ev;
}

// ---------------- propagate: weighted gather + /denom + ELU -> bf16 -------
__global__ __launch_bounds__(256) void propagate_elu(
    const int* __restrict__ offs, const int* __restrict__ csr_src,
    const float* __restrict__ csr_e, const float* __restrict__ denom,
    const float* __restrict__ feat, u16* __restrict__ out) {
  int nd = blockIdx.x;
  int f  = threadIdx.x;
  int beg = offs[nd], end = offs[nd + 1];
  float acc = 0.f;
  for (int e = beg; e < end; ++e) {
    int   s  = csr_src[e];
    float ev = csr_e[e];
    acc += ev * feat[(size_t)s * HID + f];
  }
  float r = acc / (denom[nd] + 1e-16f);
  r = (r > 0.f) ? r : expm1f(r);
  out[(size_t)nd * HID + f] = f2bf(r);
}

// ---------------- launch ----------------
extern "C" void kernel_launch(void* const* d_in, const int* in_sizes, int n_in,
                              void* d_out, int out_size, void* d_ws, size_t ws_size,
                              hipStream_t stream) {
  const void* X    = d_in[0];
  const void* W1   = d_in[1];
  const void* W2   = d_in[2];
  const void* atts = d_in[3];
  const void* attd = d_in[4];
  const int*  eidx = (const int*)d_in[5];
  const int*  esrc = eidx;
  const int*  edst = eidx + N_EDGES;

  char*  ws  = (char*)d_ws;
  size_t off = 0;
  auto alloc = [&](size_t bytes) -> void* {
    void* p = ws + off;
    off += (bytes + 255) & ~(size_t)255;
    return p;
  };
  u16*   Xb     = (u16*)alloc((size_t)N_NODES * IN_DIM * 2);
  u16*   W1b    = (u16*)alloc((size_t)HID * IN_DIM * 2);
  u16*   W2b    = (u16*)alloc((size_t)OUT_DIM * HID * 2);
  u16*   attsb  = (u16*)alloc(HID * 2);
  u16*   attdb  = (u16*)alloc(HID * 2);
  u16*   W1T    = (u16*)alloc((size_t)IN_DIM * HID * 2);
  u16*   W2T    = (u16*)alloc((size_t)HID * OUT_DIM * 2);
  float* h1p    = (float*)alloc((size_t)N_NODES * HID * 4);  // reused as h3p
  u16*   h1     = (u16*)alloc((size_t)N_NODES * HID * 2);    // reused as h3
  u16*   h2b    = (u16*)alloc((size_t)N_NODES * OUT_DIM * 2);
  float* a_s    = (float*)alloc(N_NODES * 4);
  float* a_d    = (float*)alloc(N_NODES * 4);
  float* denom  = (float*)alloc(N_NODES * 4);   // contiguous zero region start
  int*   counts = (int*)alloc(N_NODES * 4);     // zero region end
  int*   offsets= (int*)alloc((N_NODES + 1) * 4);
  int*   cursor = (int*)alloc(N_NODES * 4);
  int*   bsums  = (int*)alloc(1024 * 4);
  int*   boffs  = (int*)alloc(1024 * 4);
  int*   csrsrc = (int*)alloc((size_t)N_EDGES * 4);
  float* csre   = (float*)alloc((size_t)N_EDGES * 4);
  int*   flag   = (int*)alloc(256);
  (void)ws_size; (void)in_sizes; (void)n_in; (void)out_size;

  size_t zero_bytes = (size_t)((char*)offsets - (char*)denom);
  hipMemsetAsync(denom, 0, zero_bytes, stream);

  detect_dtype<<<1, 256, 0, stream>>>((const u32*)X, flag);

  cvt_to_bf16<<<(N_NODES * IN_DIM + 255) / 256, 256, 0, stream>>>(X, Xb, N_NODES * IN_DIM, flag);
  cvt_to_bf16<<<(HID * IN_DIM + 255) / 256, 256, 0, stream>>>(W1, W1b, HID * IN_DIM, flag);
  cvt_to_bf16<<<(OUT_DIM * HID + 255) / 256, 256, 0, stream>>>(W2, W2b, OUT_DIM * HID, flag);
  cvt_to_bf16<<<1, 256, 0, stream>>>(atts, attsb, HID, flag);
  cvt_to_bf16<<<1, 256, 0, stream>>>(attd, attdb, HID, flag);

  transpose_bf16<<<(HID * IN_DIM + 255) / 256, 256, 0, stream>>>(W1b, W1T, HID, IN_DIM);
  transpose_bf16<<<(OUT_DIM * HID + 255) / 256, 256, 0, stream>>>(W2b, W2T, OUT_DIM, HID);

  const int MBLK = (N_NODES + 63) / 64;
  // h1p = X @ W1^T  [50000,256] fp32
  gemm_nt<0><<<dim3(MBLK, HID / 64), 256, 0, stream>>>(Xb, W1b, h1p, nullptr, 0, nullptr, flag,
                                                       N_NODES, HID, IN_DIM);
  attn_dots<<<N_NODES / 4, 256, 0, stream>>>(h1p, attsb, attdb, a_s, a_d);

  const int NB = (N_NODES + 255) / 256;
  hist_kernel<<<(N_EDGES + 255) / 256, 256, 0, stream>>>(edst, counts);
  block_sum<<<NB, 256, 0, stream>>>(counts, N_NODES, bsums);
  scan_bsums<<<1, 256, 0, stream>>>(bsums, NB, boffs);
  scan_final<<<NB, 256, 0, stream>>>(counts, boffs, N_NODES, offsets, cursor);
  edge_scatter<<<(N_EDGES + 255) / 256, 256, 0, stream>>>(esrc, edst, a_s, a_d,
                                                          denom, cursor, csrsrc, csre);
  // h1 = elu(prop(h1p)) -> bf16
  propagate_elu<<<N_NODES, 256, 0, stream>>>(offsets, csrsrc, csre, denom, h1p, h1);
  // h2 = h1 @ W2^T -> d_out[0:3.2M] (dual dtype) + bf16 copy for GEMM3
  gemm_nt<2><<<dim3(MBLK, OUT_DIM / 64), 256, 0, stream>>>(h1, W2b, nullptr, d_out, 0, h2b, flag,
                                                           N_NODES, OUT_DIM, HID);
  // h3p = h2 @ W2 = h2 @ (W2T)^T  [50000,256] fp32 (reuse h1p)
  gemm_nt<0><<<dim3(MBLK, HID / 64), 256, 0, stream>>>(h2b, W2T, h1p, nullptr, 0, nullptr, flag,
                                                       N_NODES, HID, OUT_DIM);
  // h3 = elu(prop(h3p)) -> bf16 (reuse h1)
  propagate_elu<<<N_NODES, 256, 0, stream>>>(offsets, csrsrc, csre, denom, h1p, h1);
  // h4 = h3 @ W1 = h3 @ (W1T)^T -> d_out[3.2M:] (dual dtype)
  gemm_nt<1><<<dim3(MBLK, IN_DIM / 64), 256, 0, stream>>>(h1, W1T, nullptr, d_out,
                                                          (size_t)N_NODES * OUT_DIM, nullptr, flag,
                                                          N_NODES, IN_DIM, HID);
}

// Round 3
// 491.517 us; speedup vs baseline: 1.3508x; 1.3508x over previous
//
#include <hip/hip_runtime.h>
#include <hip/hip_bf16.h>

typedef unsigned short u16;
typedef unsigned int   u32;

#define N_NODES 50000
#define N_EDGES 500000
#define IN_DIM  512
#define HID     256
#define OUT_DIM 64

typedef __bf16 bf16x8 __attribute__((ext_vector_type(8)));
typedef float  f32x4  __attribute__((ext_vector_type(4)));

#define GLOBAL_AS __attribute__((address_space(1)))
#define LDS_AS    __attribute__((address_space(3)))

__device__ __forceinline__ float bf2f(u16 u) {
  union { u32 i; float f; } x; x.i = ((u32)u) << 16; return x.f;
}
__device__ __forceinline__ u16 f2bf(float f) {
  union { float f; u32 i; } x; x.f = f;
  u32 r = x.i + 0x7FFFu + ((x.i >> 16) & 1u);
  return (u16)(r >> 16);
}
__device__ __forceinline__ float lo2f(u32 w) {
  union { u32 i; float f; } x; x.i = w << 16; return x.f;
}
__device__ __forceinline__ float hi2f(u32 w) {
  union { u32 i; float f; } x; x.i = w & 0xFFFF0000u; return x.f;
}

// ---------------- dtype detector (see R2 notes; worked) ----------------
__global__ void detect_dtype(const u32* __restrict__ feat, int* __restrict__ flag) {
  __shared__ int s[256];
  int t = threadIdx.x;
  int hits = 0;
  for (int i = t; i < 1024; i += 256) {
    u32 e = (feat[i] >> 7) & 0xFF;
    hits += (e >= 100 && e <= 140) ? 1 : 0;
  }
  s[t] = hits;
  __syncthreads();
  for (int o = 128; o > 0; o >>= 1) {
    if (t < o) s[t] += s[t + o];
    __syncthreads();
  }
  if (t == 0) *flag = (s[0] > 716) ? 1 : 0;  // 1 = bf16, 0 = f32
}

// ---------------- canonicalize to bf16, 8 elems/thread ----------------
__global__ void cvt8(const void* __restrict__ src, u16* __restrict__ dst, int n8,
                     const int* __restrict__ flag) {
  int i = blockIdx.x * 256 + threadIdx.x;
  if (i >= n8) return;
  if (*flag) {
    ((uint4*)dst)[i] = ((const uint4*)src)[i];
  } else {
    const float4* s4 = (const float4*)src;
    float4 a = s4[2 * i], b = s4[2 * i + 1];
    uint4 o;
    o.x = (u32)f2bf(a.x) | ((u32)f2bf(a.y) << 16);
    o.y = (u32)f2bf(a.z) | ((u32)f2bf(a.w) << 16);
    o.z = (u32)f2bf(b.x) | ((u32)f2bf(b.y) << 16);
    o.w = (u32)f2bf(b.z) | ((u32)f2bf(b.w) << 16);
    ((uint4*)dst)[i] = o;
  }
}

// ---------------- transpose (tiny) ----------------
__global__ void transpose_bf16(const u16* __restrict__ src, u16* __restrict__ dst,
                               int R, int C) {
  int i = blockIdx.x * 256 + threadIdx.x;
  if (i < R * C) {
    int r = i / C, c = i - r * C;
    dst[c * R + r] = src[i];
  }
}

// ---------------- async 16B global->LDS ----------------
__device__ __forceinline__ void glds16(const u16* g, __bf16* l) {
  __builtin_amdgcn_global_load_lds((const GLOBAL_AS u32*)g, (LDS_AS u32*)l, 16, 0, 0);
}

// ---------------- m97-style NT GEMM: C[M,N]=A[M,K]*B[N,K]^T ----------------
// 128x128 tile, BK=32, 4 waves, each wave 64x64 (4x4 of 16x16x32 MFMAs).
// Staging via global_load_lds w=16; XOR seg-swizzle -> 2-way (free) ds_read.
// MODE 0: write bf16 to Cb.  MODE 1: write final out (f32/bf16 per *flag).
template <int MODE>
__global__ __launch_bounds__(256) void gemm128(const u16* __restrict__ A,
                                               const u16* __restrict__ B,
                                               u16* __restrict__ Cb,
                                               void* __restrict__ outbase,
                                               size_t out_off,
                                               const int* __restrict__ flag,
                                               int M, int N, int K) {
  __shared__ __bf16 As[128 * 32];  // unpadded: global_load_lds needs lane-contig
  __shared__ __bf16 Bs[128 * 32];

  const int tid  = threadIdx.x;
  const int wave = tid >> 6;
  const int lane = tid & 63;
  const int m0   = blockIdx.x * 128;
  const int n0   = blockIdx.y * 128;
  const int wm   = (wave >> 1) * 64;
  const int wn   = (wave & 1) * 64;
  const int quad = lane >> 4;
  const int l16  = lane & 15;

  // staging: wave w stages chunks {w, w+4}; chunk q = 16 rows (1 KB).
  // lane l -> row l>>2, swizzled col-seg (l&3)^((l>>3)&3) of 8 elems.
  const int r_in  = lane >> 2;
  const int s_log = (lane & 3) ^ ((lane >> 3) & 3);
  const int q0 = wave, q1 = wave + 4;
  int ar0 = m0 + q0 * 16 + r_in; if (ar0 >= M) ar0 = M - 1;
  int ar1 = m0 + q1 * 16 + r_in; if (ar1 >= M) ar1 = M - 1;
  const u16* ap0 = A + (size_t)ar0 * K + s_log * 8;
  const u16* ap1 = A + (size_t)ar1 * K + s_log * 8;
  const u16* bp0 = B + (size_t)(n0 + q0 * 16 + r_in) * K + s_log * 8;
  const u16* bp1 = B + (size_t)(n0 + q1 * 16 + r_in) * K + s_log * 8;

  f32x4 acc[4][4];
#pragma unroll
  for (int i = 0; i < 4; ++i)
#pragma unroll
    for (int j = 0; j < 4; ++j) acc[i][j] = (f32x4)0.f;

  const int swz = (l16 >> 1) & 3;  // read-side seg swizzle key (row&15 = l16)

  for (int k0 = 0; k0 < K; k0 += 32) {
    __syncthreads();                       // all waves done reading prev tile
    glds16(ap0 + k0, As + q0 * 512);
    glds16(ap1 + k0, As + q1 * 512);
    glds16(bp0 + k0, Bs + q0 * 512);
    glds16(bp1 + k0, Bs + q1 * 512);
    __syncthreads();                       // drains vmcnt -> LDS tile ready

    bf16x8 af[4], bfr[4];
#pragma unroll
    for (int mi = 0; mi < 4; ++mi)
      af[mi] = *(const bf16x8*)&As[(wm + mi * 16 + l16) * 32 + ((quad ^ swz) * 8)];
#pragma unroll
    for (int ni = 0; ni < 4; ++ni)
      bfr[ni] = *(const bf16x8*)&Bs[(wn + ni * 16 + l16) * 32 + ((quad ^ swz) * 8)];
#pragma unroll
    for (int mi = 0; mi < 4; ++mi)
#pragma unroll
      for (int ni = 0; ni < 4; ++ni)
        acc[mi][ni] = __builtin_amdgcn_mfma_f32_16x16x32_bf16(
            af[mi], bfr[ni], acc[mi][ni], 0, 0, 0);
  }

  const int out_bf = (MODE == 1) ? *flag : 0;
#pragma unroll
  for (int mi = 0; mi < 4; ++mi)
#pragma unroll
    for (int ni = 0; ni < 4; ++ni)
#pragma unroll
      for (int r = 0; r < 4; ++r) {
        int gr = m0 + wm + mi * 16 + quad * 4 + r;  // row = quad*4+reg (m89)
        int gc = n0 + wn + ni * 16 + l16;           // col = lane&15
        if (gr < M) {
          float  v   = acc[mi][ni][r];
          size_t idx = (size_t)gr * N + gc;
          if (MODE == 0) {
            Cb[idx] = f2bf(v);
          } else {
            if (out_bf) ((u16*)outbase)[out_off + idx] = f2bf(v);
            else        ((float*)outbase)[out_off + idx] = v;
          }
        }
      }
}

// ---------------- 64-tile NT GEMM (verified R2) for N=64 ----------------
// MODE 2: write final out (dual dtype) + bf16 copy to Cb.
template <int MODE>
__global__ __launch_bounds__(256) void gemm_nt(const u16* __restrict__ A,
                                               const u16* __restrict__ B,
                                               float* __restrict__ Cf,
                                               void* __restrict__ outbase,
                                               size_t out_off,
                                               u16* __restrict__ Cb,
                                               const int* __restrict__ flag,
                                               int M, int N, int K) {
  __shared__ __bf16 As[64 * 48];
  __shared__ __bf16 Bs[64 * 48];

  const int tid  = threadIdx.x;
  const int m0   = blockIdx.x * 64;
  const int n0   = blockIdx.y * 64;
  const int wave = tid >> 6;
  const int lane = tid & 63;
  const int wm   = (wave >> 1) * 32;
  const int wn   = (wave & 1) * 32;
  const int quad = lane >> 4;
  const int l16  = lane & 15;

  const int srow = tid >> 2;
  const int sseg = (tid & 3) * 8;
  int arow = m0 + srow;
  if (arow >= M) arow = M - 1;
  const size_t a_base = (size_t)arow * K + sseg;
  const size_t b_base = (size_t)(n0 + srow) * K + sseg;

  f32x4 acc[2][2];
#pragma unroll
  for (int i = 0; i < 2; ++i)
#pragma unroll
    for (int j = 0; j < 2; ++j) acc[i][j] = (f32x4)0.f;

  for (int k0 = 0; k0 < K; k0 += 32) {
    uint4 av = *(const uint4*)(A + a_base + k0);
    uint4 bv = *(const uint4*)(B + b_base + k0);
    __syncthreads();
    *(uint4*)(&As[srow * 48 + sseg]) = av;
    *(uint4*)(&Bs[srow * 48 + sseg]) = bv;
    __syncthreads();

    bf16x8 af[2], bfr[2];
#pragma unroll
    for (int mi = 0; mi < 2; ++mi)
      af[mi] = *(const bf16x8*)(&As[(wm + mi * 16 + l16) * 48 + quad * 8]);
#pragma unroll
    for (int ni = 0; ni < 2; ++ni)
      bfr[ni] = *(const bf16x8*)(&Bs[(wn + ni * 16 + l16) * 48 + quad * 8]);
#pragma unroll
    for (int mi = 0; mi < 2; ++mi)
#pragma unroll
      for (int ni = 0; ni < 2; ++ni)
        acc[mi][ni] = __builtin_amdgcn_mfma_f32_16x16x32_bf16(
            af[mi], bfr[ni], acc[mi][ni], 0, 0, 0);
  }

  const int out_bf = *flag;
#pragma unroll
  for (int mi = 0; mi < 2; ++mi)
#pragma unroll
    for (int ni = 0; ni < 2; ++ni)
#pragma unroll
      for (int r = 0; r < 4; ++r) {
        int gr = m0 + wm + mi * 16 + quad * 4 + r;
        int gc = n0 + wn + ni * 16 + l16;
        if (gr < M) {
          float  v   = acc[mi][ni][r];
          size_t idx = (size_t)gr * N + gc;
          if (out_bf) ((u16*)outbase)[out_off + idx] = f2bf(v);
          else        ((float*)outbase)[out_off + idx] = v;
          if (MODE == 2) Cb[idx] = f2bf(v);
        }
      }
  (void)Cf;
}

// ---------------- node attention dots (bf16 feat) ----------------
__global__ __launch_bounds__(256) void attn_dots(const u16* __restrict__ h1,
                                                 const u16* __restrict__ atts,
                                                 const u16* __restrict__ attd,
                                                 float* __restrict__ a_s,
                                                 float* __restrict__ a_d) {
  __shared__ __align__(16) float ss[HID];
  __shared__ __align__(16) float sd[HID];
  int t = threadIdx.x;
  ss[t] = bf2f(atts[t]);
  sd[t] = bf2f(attd[t]);
  __syncthreads();
  int row  = blockIdx.x * 4 + (t >> 6);
  int lane = t & 63;
  ushort4 h = ((const ushort4*)(h1 + (size_t)row * HID))[lane];
  float4  s = ((const float4*)ss)[lane];
  float4  d = ((const float4*)sd)[lane];
  float hx = bf2f(h.x), hy = bf2f(h.y), hz = bf2f(h.z), hw = bf2f(h.w);
  float vs = hx * s.x + hy * s.y + hz * s.z + hw * s.w;
  float vd = hx * d.x + hy * d.y + hz * d.z + hw * d.w;
#pragma unroll
  for (int off = 32; off > 0; off >>= 1) {
    vs += __shfl_down(vs, off);
    vd += __shfl_down(vd, off);
  }
  if (lane == 0) {
    a_s[row] = vs;
    a_d[row] = vd;
  }
}

// ---------------- CSR build ----------------
__global__ void hist_kernel(const int* __restrict__ dst, int* __restrict__ counts) {
  int e = blockIdx.x * 256 + threadIdx.x;
  if (e < N_EDGES) atomicAdd(&counts[dst[e]], 1);
}

__global__ void block_sum(const int* __restrict__ counts, int n,
                          int* __restrict__ bsums) {
  __shared__ int s[256];
  int i = blockIdx.x * 256 + threadIdx.x;
  s[threadIdx.x] = (i < n) ? counts[i] : 0;
  __syncthreads();
  for (int off = 128; off > 0; off >>= 1) {
    if (threadIdx.x < off) s[threadIdx.x] += s[threadIdx.x + off];
    __syncthreads();
  }
  if (threadIdx.x == 0) bsums[blockIdx.x] = s[0];
}

__global__ void scan_bsums(const int* __restrict__ bsums, int nb,
                           int* __restrict__ boffs) {
  __shared__ int s[256];
  int t = threadIdx.x;
  int v = (t < nb) ? bsums[t] : 0;
  s[t] = v;
  __syncthreads();
  for (int off = 1; off < 256; off <<= 1) {
    int add = (t >= off) ? s[t - off] : 0;
    __syncthreads();
    s[t] += add;
    __syncthreads();
  }
  boffs[t] = s[t] - v;  // exclusive
}

__global__ void scan_final(const int* __restrict__ counts,
                           const int* __restrict__ boffs, int n,
                           int* __restrict__ offsets, int* __restrict__ cursor) {
  __shared__ int s[256];
  int t = threadIdx.x;
  int i = blockIdx.x * 256 + t;
  int v = (i < n) ? counts[i] : 0;
  s[t] = v;
  __syncthreads();
  for (int off = 1; off < 256; off <<= 1) {
    int add = (t >= off) ? s[t - off] : 0;
    __syncthreads();
    s[t] += add;
    __syncthreads();
  }
  int excl = boffs[blockIdx.x] + s[t] - v;
  if (i < n) {
    offsets[i] = excl;
    cursor[i]  = excl;
  }
  if (i == n - 1) offsets[n] = excl + v;
}

// a = sigmoid(.) in (0,1) -> exp never overflows; segment-max cancels.
__global__ void edge_scatter(const int* __restrict__ src, const int* __restrict__ dst,
                             const float* __restrict__ a_s, const float* __restrict__ a_d,
                             float* __restrict__ denom, int* __restrict__ cursor,
                             int* __restrict__ csr_src, float* __restrict__ csr_e) {
  int e = blockIdx.x * 256 + threadIdx.x;
  if (e >= N_EDGES) return;
  int s = src[e], d = dst[e];
  float x  = a_s[s] + a_d[d];
  float a  = 1.f / (1.f + expf(-x));
  float ev = expf(a);
  atomicAdd(&denom[d], ev);
  int pos = atomicAdd(&cursor[d], 1);
  csr_src[pos] = s;
  csr_e[pos]   = ev;
}

// ---------------- propagate: bf16 gather, 32-lane subgroup per node -------
// 8 nodes/block; lane handles 8 feats via one 16B load per edge.
__global__ __launch_bounds__(256) void propagate_elu8(
    const int* __restrict__ offs, const int* __restrict__ csr_src,
    const float* __restrict__ csr_e, const float* __restrict__ denom,
    const u16* __restrict__ feat, u16* __restrict__ out) {
  const int sub  = threadIdx.x >> 5;
  const int lane = threadIdx.x & 31;
  const int nd   = blockIdx.x * 8 + sub;
  const int col  = lane * 8;
  const int beg = offs[nd], end = offs[nd + 1];
  float a[8];
#pragma unroll
  for (int j = 0; j < 8; ++j) a[j] = 0.f;
  for (int e = beg; e < end; ++e) {
    int   s  = csr_src[e];
    float ev = csr_e[e];
    uint4 w = *(const uint4*)(feat + (size_t)s * HID + col);
    a[0] += ev * lo2f(w.x); a[1] += ev * hi2f(w.x);
    a[2] += ev * lo2f(w.y); a[3] += ev * hi2f(w.y);
    a[4] += ev * lo2f(w.z); a[5] += ev * hi2f(w.z);
    a[6] += ev * lo2f(w.w); a[7] += ev * hi2f(w.w);
  }
  float dn = 1.f / (denom[nd] + 1e-16f);
  uint4 o;
  u32 p[4];
#pragma unroll
  for (int j = 0; j < 4; ++j) {
    float r0 = a[2 * j] * dn;
    float r1 = a[2 * j + 1] * dn;
    r0 = (r0 > 0.f) ? r0 : expm1f(r0);
    r1 = (r1 > 0.f) ? r1 : expm1f(r1);
    p[j] = (u32)f2bf(r0) | ((u32)f2bf(r1) << 16);
  }
  o.x = p[0]; o.y = p[1]; o.z = p[2]; o.w = p[3];
  *(uint4*)(out + (size_t)nd * HID + col) = o;
}

// ---------------- launch ----------------
extern "C" void kernel_launch(void* const* d_in, const int* in_sizes, int n_in,
                              void* d_out, int out_size, void* d_ws, size_t ws_size,
                              hipStream_t stream) {
  const void* X    = d_in[0];
  const void* W1   = d_in[1];
  const void* W2   = d_in[2];
  const void* atts = d_in[3];
  const void* attd = d_in[4];
  const int*  eidx = (const int*)d_in[5];
  const int*  esrc = eidx;
  const int*  edst = eidx + N_EDGES;

  char*  ws  = (char*)d_ws;
  size_t off = 0;
  auto alloc = [&](size_t bytes) -> void* {
    void* p = ws + off;
    off += (bytes + 255) & ~(size_t)255;
    return p;
  };
  u16*   Xb     = (u16*)alloc((size_t)N_NODES * IN_DIM * 2);
  u16*   W1b    = (u16*)alloc((size_t)HID * IN_DIM * 2);
  u16*   W2b    = (u16*)alloc((size_t)OUT_DIM * HID * 2);
  u16*   attsb  = (u16*)alloc(HID * 2);
  u16*   attdb  = (u16*)alloc(HID * 2);
  u16*   W1T    = (u16*)alloc((size_t)IN_DIM * HID * 2);
  u16*   W2T    = (u16*)alloc((size_t)HID * OUT_DIM * 2);
  u16*   feat   = (u16*)alloc((size_t)N_NODES * HID * 2);   // h1p / h3p (bf16)
  u16*   h1     = (u16*)alloc((size_t)N_NODES * HID * 2);   // h1 / h3
  u16*   h2b    = (u16*)alloc((size_t)N_NODES * OUT_DIM * 2);
  float* a_s    = (float*)alloc(N_NODES * 4);
  float* a_d    = (float*)alloc(N_NODES * 4);
  float* denom  = (float*)alloc(N_NODES * 4);   // zero region start
  int*   counts = (int*)alloc(N_NODES * 4);     // zero region end
  int*   offsets= (int*)alloc((N_NODES + 1) * 4);
  int*   cursor = (int*)alloc(N_NODES * 4);
  int*   bsums  = (int*)alloc(1024 * 4);
  int*   boffs  = (int*)alloc(1024 * 4);
  int*   csrsrc = (int*)alloc((size_t)N_EDGES * 4);
  float* csre   = (float*)alloc((size_t)N_EDGES * 4);
  int*   flag   = (int*)alloc(256);
  (void)ws_size; (void)in_sizes; (void)n_in; (void)out_size;

  size_t zero_bytes = (size_t)((char*)offsets - (char*)denom);
  hipMemsetAsync(denom, 0, zero_bytes, stream);

  detect_dtype<<<1, 256, 0, stream>>>((const u32*)X, flag);

  cvt8<<<(N_NODES * IN_DIM / 8 + 255) / 256, 256, 0, stream>>>(X, Xb, N_NODES * IN_DIM / 8, flag);
  cvt8<<<(HID * IN_DIM / 8 + 255) / 256, 256, 0, stream>>>(W1, W1b, HID * IN_DIM / 8, flag);
  cvt8<<<(OUT_DIM * HID / 8 + 255) / 256, 256, 0, stream>>>(W2, W2b, OUT_DIM * HID / 8, flag);
  cvt8<<<1, 256, 0, stream>>>(atts, attsb, HID / 8, flag);
  cvt8<<<1, 256, 0, stream>>>(attd, attdb, HID / 8, flag);

  transpose_bf16<<<(HID * IN_DIM + 255) / 256, 256, 0, stream>>>(W1b, W1T, HID, IN_DIM);
  transpose_bf16<<<(OUT_DIM * HID + 255) / 256, 256, 0, stream>>>(W2b, W2T, OUT_DIM, HID);

  const int MB128 = (N_NODES + 127) / 128;  // 391
  const int MB64  = (N_NODES + 63) / 64;    // 782
  // h1p = X @ W1^T  [50000,256] -> bf16 feat
  gemm128<0><<<dim3(MB128, HID / 128), 256, 0, stream>>>(Xb, W1b, feat, nullptr, 0, flag,
                                                         N_NODES, HID, IN_DIM);
  attn_dots<<<N_NODES / 4, 256, 0, stream>>>(feat, attsb, attdb, a_s, a_d);

  const int NB = (N_NODES + 255) / 256;
  hist_kernel<<<(N_EDGES + 255) / 256, 256, 0, stream>>>(edst, counts);
  block_sum<<<NB, 256, 0, stream>>>(counts, N_NODES, bsums);
  scan_bsums<<<1, 256, 0, stream>>>(bsums, NB, boffs);
  scan_final<<<NB, 256, 0, stream>>>(counts, boffs, N_NODES, offsets, cursor);
  edge_scatter<<<(N_EDGES + 255) / 256, 256, 0, stream>>>(esrc, edst, a_s, a_d,
                                                          denom, cursor, csrsrc, csre);
  // h1 = elu(prop(h1p)) -> bf16
  propagate_elu8<<<N_NODES / 8, 256, 0, stream>>>(offsets, csrsrc, csre, denom, feat, h1);
  // h2 = h1 @ W2^T -> d_out (dual dtype) + bf16 copy
  gemm_nt<2><<<dim3(MB64, 1), 256, 0, stream>>>(h1, W2b, nullptr, d_out, 0, h2b, flag,
                                                N_NODES, OUT_DIM, HID);
  // h3p = h2 @ (W2T)^T [50000,256] -> bf16 feat (reuse)
  gemm128<0><<<dim3(MB128, HID / 128), 256, 0, stream>>>(h2b, W2T, feat, nullptr, 0, flag,
                                                         N_NODES, HID, OUT_DIM);
  // h3 = elu(prop(h3p)) -> bf16 (reuse h1)
  propagate_elu8<<<N_NODES / 8, 256, 0, stream>>>(offsets, csrsrc, csre, denom, feat, h1);
  // h4 = h3 @ (W1T)^T -> d_out tail (dual dtype)
  gemm128<1><<<dim3(MB128, IN_DIM / 128), 256, 0, stream>>>(h1, W1T, nullptr, d_out,
                                                            (size_t)N_NODES * OUT_DIM, flag,
                                                            N_NODES, IN_DIM, HID);
}

// Round 4
// 461.611 us; speedup vs baseline: 1.4383x; 1.0648x over previous
//
#include <hip/hip_runtime.h>
#include <hip/hip_bf16.h>

typedef unsigned short u16;
typedef unsigned int   u32;

#define N_NODES 50000
#define N_EDGES 500000
#define IN_DIM  512
#define HID     256
#define OUT_DIM 64

typedef __bf16 bf16x8 __attribute__((ext_vector_type(8)));
typedef float  f32x4  __attribute__((ext_vector_type(4)));

#define GLOBAL_AS __attribute__((address_space(1)))
#define LDS_AS    __attribute__((address_space(3)))

__device__ __forceinline__ float bf2f(u16 u) {
  union { u32 i; float f; } x; x.i = ((u32)u) << 16; return x.f;
}
__device__ __forceinline__ u16 f2bf(float f) {
  union { float f; u32 i; } x; x.f = f;
  u32 r = x.i + 0x7FFFu + ((x.i >> 16) & 1u);
  return (u16)(r >> 16);
}
__device__ __forceinline__ float lo2f(u32 w) {
  union { u32 i; float f; } x; x.i = w << 16; return x.f;
}
__device__ __forceinline__ float hi2f(u32 w) {
  union { u32 i; float f; } x; x.i = w & 0xFFFF0000u; return x.f;
}

// ---------------- dtype detector (validated R2/R3) ----------------
__global__ void detect_dtype(const u32* __restrict__ feat, int* __restrict__ flag) {
  __shared__ int s[256];
  int t = threadIdx.x;
  int hits = 0;
  for (int i = t; i < 1024; i += 256) {
    u32 e = (feat[i] >> 7) & 0xFF;
    hits += (e >= 100 && e <= 140) ? 1 : 0;
  }
  s[t] = hits;
  __syncthreads();
  for (int o = 128; o > 0; o >>= 1) {
    if (t < o) s[t] += s[t + o];
    __syncthreads();
  }
  if (t == 0) *flag = (s[0] > 716) ? 1 : 0;  // 1 = bf16, 0 = f32
}

// ---------------- X -> bf16 (f32 mode only; bf16 mode reads X directly) ----
__global__ void cvt8_cond(const void* __restrict__ src, u16* __restrict__ dst,
                          int n8, const int* __restrict__ flag) {
  if (*flag) return;  // bf16 mode: consumer reads raw pointer
  int i = blockIdx.x * 256 + threadIdx.x;
  if (i >= n8) return;
  const float4* s4 = (const float4*)src;
  float4 a = s4[2 * i], b = s4[2 * i + 1];
  uint4 o;
  o.x = (u32)f2bf(a.x) | ((u32)f2bf(a.y) << 16);
  o.y = (u32)f2bf(a.z) | ((u32)f2bf(a.w) << 16);
  o.z = (u32)f2bf(b.x) | ((u32)f2bf(b.y) << 16);
  o.w = (u32)f2bf(b.z) | ((u32)f2bf(b.w) << 16);
  ((uint4*)dst)[i] = o;
}

// ---------------- one-shot weight/attn prep: convert + transposes ----------
__global__ void prep(const void* __restrict__ W1r, const void* __restrict__ W2r,
                     const void* __restrict__ atsr, const void* __restrict__ atdr,
                     u16* __restrict__ W1b, u16* __restrict__ W2b,
                     u16* __restrict__ attsb, u16* __restrict__ attdb,
                     u16* __restrict__ W1T, u16* __restrict__ W2T,
                     const int* __restrict__ flag) {
  const int fv = *flag;
  int i = blockIdx.x * 256 + threadIdx.x;
  int stride = gridDim.x * 256;
  const int NW1 = HID * IN_DIM;   // 131072
  const int NW2 = OUT_DIM * HID;  // 16384
  for (int j = i; j < NW1; j += stride) {
    u16 v = fv ? ((const u16*)W1r)[j] : f2bf(((const float*)W1r)[j]);
    W1b[j] = v;
    int r = j >> 9, c = j & 511;        // j / IN_DIM, j % IN_DIM
    W1T[c * HID + r] = v;
  }
  for (int j = i; j < NW2; j += stride) {
    u16 v = fv ? ((const u16*)W2r)[j] : f2bf(((const float*)W2r)[j]);
    W2b[j] = v;
    int r = j >> 8, c = j & 255;        // j / HID, j % HID
    W2T[c * OUT_DIM + r] = v;
  }
  if (blockIdx.x == 0 && threadIdx.x < HID) {
    int t = threadIdx.x;
    attsb[t] = fv ? ((const u16*)atsr)[t] : f2bf(((const float*)atsr)[t]);
    attdb[t] = fv ? ((const u16*)atdr)[t] : f2bf(((const float*)atdr)[t]);
  }
}

// ---------------- async 16B global->LDS ----------------
__device__ __forceinline__ void glds16(const u16* g, __bf16* l) {
  __builtin_amdgcn_global_load_lds((const GLOBAL_AS u32*)g, (LDS_AS u32*)l, 16, 0, 0);
}

// ---------------- m97-style NT GEMM: C[M,N]=A[M,K]*B[N,K]^T ----------------
// 128x128 tile, BK=32, 4 waves, 4x4 16x16x32 MFMAs per wave.
// MODE 1: final out (f32/bf16 per *flag) at outbase+out_off
// MODE 2: bf16 -> Cb with fused ELU
// MODE 3: bf16 -> Cb + fused attention dots (atomicAdd partials to a_s/a_d)
template <int MODE>
__global__ __launch_bounds__(256) void gemm128(const u16* __restrict__ A,
                                               const u16* __restrict__ Aalt,
                                               const u16* __restrict__ B,
                                               u16* __restrict__ Cb,
                                               void* __restrict__ outbase,
                                               size_t out_off,
                                               const u16* __restrict__ attsb,
                                               const u16* __restrict__ attdb,
                                               float* __restrict__ a_s,
                                               float* __restrict__ a_d,
                                               const int* __restrict__ flag,
                                               int M, int N, int K) {
  __shared__ __bf16 As[128 * 32];
  __shared__ __bf16 Bs[128 * 32];
  __shared__ float as_l[128];
  __shared__ float ad_l[128];

  const int fv = *flag;
  if (Aalt && fv) A = Aalt;  // bf16 mode: read raw input directly

  const int tid  = threadIdx.x;
  const int wave = tid >> 6;
  const int lane = tid & 63;
  const int m0   = blockIdx.x * 128;
  const int n0   = blockIdx.y * 128;
  const int wm   = (wave >> 1) * 64;
  const int wn   = (wave & 1) * 64;
  const int quad = lane >> 4;
  const int l16  = lane & 15;

  if (MODE == 3 && tid < 128) {
    as_l[tid] = bf2f(attsb[n0 + tid]);
    ad_l[tid] = bf2f(attdb[n0 + tid]);
  }

  const int r_in  = lane >> 2;
  const int s_log = (lane & 3) ^ ((lane >> 3) & 3);
  const int q0 = wave, q1 = wave + 4;
  int ar0 = m0 + q0 * 16 + r_in; if (ar0 >= M) ar0 = M - 1;
  int ar1 = m0 + q1 * 16 + r_in; if (ar1 >= M) ar1 = M - 1;
  const u16* ap0 = A + (size_t)ar0 * K + s_log * 8;
  const u16* ap1 = A + (size_t)ar1 * K + s_log * 8;
  const u16* bp0 = B + (size_t)(n0 + q0 * 16 + r_in) * K + s_log * 8;
  const u16* bp1 = B + (size_t)(n0 + q1 * 16 + r_in) * K + s_log * 8;

  f32x4 acc[4][4];
#pragma unroll
  for (int i = 0; i < 4; ++i)
#pragma unroll
    for (int j = 0; j < 4; ++j) acc[i][j] = (f32x4)0.f;

  const int swz = (l16 >> 1) & 3;

  for (int k0 = 0; k0 < K; k0 += 32) {
    __syncthreads();
    glds16(ap0 + k0, As + q0 * 512);
    glds16(ap1 + k0, As + q1 * 512);
    glds16(bp0 + k0, Bs + q0 * 512);
    glds16(bp1 + k0, Bs + q1 * 512);
    __syncthreads();

    bf16x8 af[4], bfr[4];
#pragma unroll
    for (int mi = 0; mi < 4; ++mi)
      af[mi] = *(const bf16x8*)&As[(wm + mi * 16 + l16) * 32 + ((quad ^ swz) * 8)];
#pragma unroll
    for (int ni = 0; ni < 4; ++ni)
      bfr[ni] = *(const bf16x8*)&Bs[(wn + ni * 16 + l16) * 32 + ((quad ^ swz) * 8)];
#pragma unroll
    for (int mi = 0; mi < 4; ++mi)
#pragma unroll
      for (int ni = 0; ni < 4; ++ni)
        acc[mi][ni] = __builtin_amdgcn_mfma_f32_16x16x32_bf16(
            af[mi], bfr[ni], acc[mi][ni], 0, 0, 0);
  }

  if (MODE == 3) {
    __syncthreads();  // as_l/ad_l visible (loaded pre-loop, barrier-covered anyway)
#pragma unroll
    for (int mi = 0; mi < 4; ++mi)
#pragma unroll
      for (int r = 0; r < 4; ++r) {
        float ps = 0.f, pd = 0.f;
#pragma unroll
        for (int ni = 0; ni < 4; ++ni) {
          int c = wn + ni * 16 + l16;
          ps += acc[mi][ni][r] * as_l[c];
          pd += acc[mi][ni][r] * ad_l[c];
        }
#pragma unroll
        for (int o = 1; o < 16; o <<= 1) {
          ps += __shfl_xor(ps, o);
          pd += __shfl_xor(pd, o);
        }
        int gr = m0 + wm + mi * 16 + quad * 4 + r;
        if (l16 == 0 && gr < M) {
          atomicAdd(&a_s[gr], ps);
          atomicAdd(&a_d[gr], pd);
        }
      }
  }

#pragma unroll
  for (int mi = 0; mi < 4; ++mi)
#pragma unroll
    for (int ni = 0; ni < 4; ++ni)
#pragma unroll
      for (int r = 0; r < 4; ++r) {
        int gr = m0 + wm + mi * 16 + quad * 4 + r;  // row = quad*4+reg (m89)
        int gc = n0 + wn + ni * 16 + l16;           // col = lane&15
        if (gr < M) {
          float  v   = acc[mi][ni][r];
          size_t idx = (size_t)gr * N + gc;
          if (MODE == 1) {
            if (fv) ((u16*)outbase)[out_off + idx] = f2bf(v);
            else    ((float*)outbase)[out_off + idx] = v;
          } else if (MODE == 2) {
            v = (v > 0.f) ? v : expm1f(v);
            Cb[idx] = f2bf(v);
          } else {
            Cb[idx] = f2bf(v);
          }
        }
      }
}

// ---------------- 64-tile NT GEMM for N=64 (h2): dual out + bf16 copy -----
__global__ __launch_bounds__(256) void gemm_h2(const u16* __restrict__ A,
                                               const u16* __restrict__ B,
                                               void* __restrict__ outbase,
                                               u16* __restrict__ Cb,
                                               const int* __restrict__ flag,
                                               int M, int N, int K) {
  __shared__ __bf16 As[64 * 48];
  __shared__ __bf16 Bs[64 * 48];

  const int tid  = threadIdx.x;
  const int m0   = blockIdx.x * 64;
  const int wave = tid >> 6;
  const int lane = tid & 63;
  const int wm   = (wave >> 1) * 32;
  const int wn   = (wave & 1) * 32;
  const int quad = lane >> 4;
  const int l16  = lane & 15;

  const int srow = tid >> 2;
  const int sseg = (tid & 3) * 8;
  int arow = m0 + srow;
  if (arow >= M) arow = M - 1;
  const size_t a_base = (size_t)arow * K + sseg;
  const size_t b_base = (size_t)srow * K + sseg;  // n0 = 0 (N=64)

  f32x4 acc[2][2];
#pragma unroll
  for (int i = 0; i < 2; ++i)
#pragma unroll
    for (int j = 0; j < 2; ++j) acc[i][j] = (f32x4)0.f;

  for (int k0 = 0; k0 < K; k0 += 32) {
    uint4 av = *(const uint4*)(A + a_base + k0);
    uint4 bv = *(const uint4*)(B + b_base + k0);
    __syncthreads();
    *(uint4*)(&As[srow * 48 + sseg]) = av;
    *(uint4*)(&Bs[srow * 48 + sseg]) = bv;
    __syncthreads();

    bf16x8 af[2], bfr[2];
#pragma unroll
    for (int mi = 0; mi < 2; ++mi)
      af[mi] = *(const bf16x8*)(&As[(wm + mi * 16 + l16) * 48 + quad * 8]);
#pragma unroll
    for (int ni = 0; ni < 2; ++ni)
      bfr[ni] = *(const bf16x8*)(&Bs[(wn + ni * 16 + l16) * 48 + quad * 8]);
#pragma unroll
    for (int mi = 0; mi < 2; ++mi)
#pragma unroll
      for (int ni = 0; ni < 2; ++ni)
        acc[mi][ni] = __builtin_amdgcn_mfma_f32_16x16x32_bf16(
            af[mi], bfr[ni], acc[mi][ni], 0, 0, 0);
  }

  const int fv = *flag;
#pragma unroll
  for (int mi = 0; mi < 2; ++mi)
#pragma unroll
    for (int ni = 0; ni < 2; ++ni)
#pragma unroll
      for (int r = 0; r < 4; ++r) {
        int gr = m0 + wm + mi * 16 + quad * 4 + r;
        int gc = wn + ni * 16 + l16;
        if (gr < M && gc < N) {
          float  v   = acc[mi][ni][r];
          size_t idx = (size_t)gr * N + gc;
          u16 bv = f2bf(v);
          if (fv) ((u16*)outbase)[idx] = bv;
          else    ((float*)outbase)[idx] = v;
          Cb[idx] = bv;
        }
      }
}

// ---------------- CSR build ----------------
__global__ void hist_kernel(const int* __restrict__ dst, int* __restrict__ counts) {
  int e = blockIdx.x * 256 + threadIdx.x;
  if (e < N_EDGES) atomicAdd(&counts[dst[e]], 1);
}

__global__ void block_sum(const int* __restrict__ counts, int n,
                          int* __restrict__ bsums) {
  __shared__ int s[256];
  int i = blockIdx.x * 256 + threadIdx.x;
  s[threadIdx.x] = (i < n) ? counts[i] : 0;
  __syncthreads();
  for (int off = 128; off > 0; off >>= 1) {
    if (threadIdx.x < off) s[threadIdx.x] += s[threadIdx.x + off];
    __syncthreads();
  }
  if (threadIdx.x == 0) bsums[blockIdx.x] = s[0];
}

__global__ void scan_bsums(const int* __restrict__ bsums, int nb,
                           int* __restrict__ boffs) {
  __shared__ int s[256];
  int t = threadIdx.x;
  int v = (t < nb) ? bsums[t] : 0;
  s[t] = v;
  __syncthreads();
  for (int off = 1; off < 256; off <<= 1) {
    int add = (t >= off) ? s[t - off] : 0;
    __syncthreads();
    s[t] += add;
    __syncthreads();
  }
  boffs[t] = s[t] - v;  // exclusive
}

__global__ void scan_final(const int* __restrict__ counts,
                           const int* __restrict__ boffs, int n,
                           int* __restrict__ offsets, int* __restrict__ cursor) {
  __shared__ int s[256];
  int t = threadIdx.x;
  int i = blockIdx.x * 256 + t;
  int v = (i < n) ? counts[i] : 0;
  s[t] = v;
  __syncthreads();
  for (int off = 1; off < 256; off <<= 1) {
    int add = (t >= off) ? s[t - off] : 0;
    __syncthreads();
    s[t] += add;
    __syncthreads();
  }
  int excl = boffs[blockIdx.x] + s[t] - v;
  if (i < n) {
    offsets[i] = excl;
    cursor[i]  = excl;
  }
  if (i == n - 1) offsets[n] = excl + v;
}

// sigmoid in (0,1) -> exp never overflows; segment-max cancels in softmax.
__global__ void edge_scatter(const int* __restrict__ src, const int* __restrict__ dst,
                             const float* __restrict__ a_s, const float* __restrict__ a_d,
                             float* __restrict__ denom, int* __restrict__ cursor,
                             int2* __restrict__ edges) {
  int e = blockIdx.x * 256 + threadIdx.x;
  if (e >= N_EDGES) return;
  int s = src[e], d = dst[e];
  float x  = a_s[s] + a_d[d];
  float a  = 1.f / (1.f + expf(-x));
  float ev = expf(a);
  atomicAdd(&denom[d], ev);
  int pos = atomicAdd(&cursor[d], 1);
  edges[pos] = make_int2(s, __float_as_int(ev));
}

// ---------------- prop 256-dim: 32-lane subgroup/node, fused ELU ----------
__global__ __launch_bounds__(256) void prop256(
    const int* __restrict__ offs, const int2* __restrict__ edges,
    const float* __restrict__ denom, const u16* __restrict__ feat,
    u16* __restrict__ out) {
  const int sub  = threadIdx.x >> 5;
  const int lane = threadIdx.x & 31;
  const int nd   = blockIdx.x * 8 + sub;
  const int col  = lane * 8;
  const int beg = offs[nd], end = offs[nd + 1];
  float a[8];
#pragma unroll
  for (int j = 0; j < 8; ++j) a[j] = 0.f;
  for (int e = beg; e < end; ++e) {
    int2  ed = edges[e];
    float ev = __int_as_float(ed.y);
    uint4 w = *(const uint4*)(feat + (size_t)ed.x * HID + col);
    a[0] += ev * lo2f(w.x); a[1] += ev * hi2f(w.x);
    a[2] += ev * lo2f(w.y); a[3] += ev * hi2f(w.y);
    a[4] += ev * lo2f(w.z); a[5] += ev * hi2f(w.z);
    a[6] += ev * lo2f(w.w); a[7] += ev * hi2f(w.w);
  }
  float dn = 1.f / (denom[nd] + 1e-16f);
  u32 p[4];
#pragma unroll
  for (int j = 0; j < 4; ++j) {
    float r0 = a[2 * j] * dn;
    float r1 = a[2 * j + 1] * dn;
    r0 = (r0 > 0.f) ? r0 : expm1f(r0);
    r1 = (r1 > 0.f) ? r1 : expm1f(r1);
    p[j] = (u32)f2bf(r0) | ((u32)f2bf(r1) << 16);
  }
  *(uint4*)(out + (size_t)nd * HID + col) = make_uint4(p[0], p[1], p[2], p[3]);
}

// ---------------- prop 64-dim (on h2): 8-lane subgroup/node, no ELU -------
__global__ __launch_bounds__(256) void prop64(
    const int* __restrict__ offs, const int2* __restrict__ edges,
    const float* __restrict__ denom, const u16* __restrict__ feat,
    u16* __restrict__ out) {
  const int sub  = threadIdx.x >> 3;
  const int lane = threadIdx.x & 7;
  const int nd   = blockIdx.x * 32 + sub;
  if (nd >= N_NODES) return;
  const int col  = lane * 8;
  const int beg = offs[nd], end = offs[nd + 1];
  float a[8];
#pragma unroll
  for (int j = 0; j < 8; ++j) a[j] = 0.f;
  for (int e = beg; e < end; ++e) {
    int2  ed = edges[e];
    float ev = __int_as_float(ed.y);
    uint4 w = *(const uint4*)(feat + (size_t)ed.x * OUT_DIM + col);
    a[0] += ev * lo2f(w.x); a[1] += ev * hi2f(w.x);
    a[2] += ev * lo2f(w.y); a[3] += ev * hi2f(w.y);
    a[4] += ev * lo2f(w.z); a[5] += ev * hi2f(w.z);
    a[6] += ev * lo2f(w.w); a[7] += ev * hi2f(w.w);
  }
  float dn = 1.f / (denom[nd] + 1e-16f);
  u32 p[4];
#pragma unroll
  for (int j = 0; j < 4; ++j) {
    p[j] = (u32)f2bf(a[2 * j] * dn) | ((u32)f2bf(a[2 * j + 1] * dn) << 16);
  }
  *(uint4*)(out + (size_t)nd * OUT_DIM + col) = make_uint4(p[0], p[1], p[2], p[3]);
}

// ---------------- launch ----------------
extern "C" void kernel_launch(void* const* d_in, const int* in_sizes, int n_in,
                              void* d_out, int out_size, void* d_ws, size_t ws_size,
                              hipStream_t stream) {
  const void* X    = d_in[0];
  const void* W1   = d_in[1];
  const void* W2   = d_in[2];
  const void* atts = d_in[3];
  const void* attd = d_in[4];
  const int*  eidx = (const int*)d_in[5];
  const int*  esrc = eidx;
  const int*  edst = eidx + N_EDGES;

  char*  ws  = (char*)d_ws;
  size_t off = 0;
  auto alloc = [&](size_t bytes) -> void* {
    void* p = ws + off;
    off += (bytes + 255) & ~(size_t)255;
    return p;
  };
  u16*   Xb     = (u16*)alloc((size_t)N_NODES * IN_DIM * 2);
  u16*   W1b    = (u16*)alloc((size_t)HID * IN_DIM * 2);
  u16*   W2b    = (u16*)alloc((size_t)OUT_DIM * HID * 2);
  u16*   attsb  = (u16*)alloc(HID * 2);
  u16*   attdb  = (u16*)alloc(HID * 2);
  u16*   W1T    = (u16*)alloc((size_t)IN_DIM * HID * 2);
  u16*   W2T    = (u16*)alloc((size_t)HID * OUT_DIM * 2);
  u16*   feat   = (u16*)alloc((size_t)N_NODES * HID * 2);   // h1p, later h3
  u16*   h1     = (u16*)alloc((size_t)N_NODES * HID * 2);
  u16*   h2b    = (u16*)alloc((size_t)N_NODES * OUT_DIM * 2);
  u16*   ph2    = (u16*)alloc((size_t)N_NODES * OUT_DIM * 2);
  float* a_s    = (float*)alloc(N_NODES * 4);   // zero region start
  float* a_d    = (float*)alloc(N_NODES * 4);
  float* denom  = (float*)alloc(N_NODES * 4);
  int*   counts = (int*)alloc(N_NODES * 4);     // zero region end
  int*   offsets= (int*)alloc((N_NODES + 1) * 4);
  int*   cursor = (int*)alloc(N_NODES * 4);
  int*   bsums  = (int*)alloc(1024 * 4);
  int*   boffs  = (int*)alloc(1024 * 4);
  int2*  edges  = (int2*)alloc((size_t)N_EDGES * 8);
  int*   flag   = (int*)alloc(256);
  (void)ws_size; (void)in_sizes; (void)n_in; (void)out_size;

  size_t zero_bytes = (size_t)((char*)offsets - (char*)a_s);
  hipMemsetAsync(a_s, 0, zero_bytes, stream);

  detect_dtype<<<1, 256, 0, stream>>>((const u32*)X, flag);
  cvt8_cond<<<(N_NODES * IN_DIM / 8 + 255) / 256, 256, 0, stream>>>(
      X, Xb, N_NODES * IN_DIM / 8, flag);
  prep<<<512, 256, 0, stream>>>(W1, W2, atts, attd, W1b, W2b, attsb, attdb,
                                W1T, W2T, flag);

  const int MB128 = (N_NODES + 127) / 128;  // 391
  const int MB64  = (N_NODES + 63) / 64;    // 782

  // h1p = X @ W1^T -> feat (bf16), fused attention dots -> a_s/a_d
  gemm128<3><<<dim3(MB128, HID / 128), 256, 0, stream>>>(
      Xb, (const u16*)X, W1b, feat, nullptr, 0, attsb, attdb, a_s, a_d, flag,
      N_NODES, HID, IN_DIM);

  // CSR by dst + edge weights
  const int NB = (N_NODES + 255) / 256;
  hist_kernel<<<(N_EDGES + 255) / 256, 256, 0, stream>>>(edst, counts);
  block_sum<<<NB, 256, 0, stream>>>(counts, N_NODES, bsums);
  scan_bsums<<<1, 256, 0, stream>>>(bsums, NB, boffs);
  scan_final<<<NB, 256, 0, stream>>>(counts, boffs, N_NODES, offsets, cursor);
  edge_scatter<<<(N_EDGES + 255) / 256, 256, 0, stream>>>(esrc, edst, a_s, a_d,
                                                          denom, cursor, edges);

  // h1 = elu(P . h1p)
  prop256<<<N_NODES / 8, 256, 0, stream>>>(offsets, edges, denom, feat, h1);
  // h2 = h1 @ W2^T -> d_out (dual) + h2b (bf16)
  gemm_h2<<<dim3(MB64, 1), 256, 0, stream>>>(h1, W2b, d_out, h2b, flag,
                                             N_NODES, OUT_DIM, HID);
  // ph2 = P . h2   (64-dim propagate; commutes with @W2 since ELU is outside)
  prop64<<<(N_NODES + 31) / 32, 256, 0, stream>>>(offsets, edges, denom, h2b, ph2);
  // h3 = elu(ph2 @ W2) = elu(P . (h2 @ W2))  -> feat buffer (bf16)
  gemm128<2><<<dim3(MB128, HID / 128), 256, 0, stream>>>(
      ph2, nullptr, W2T, feat, nullptr, 0, nullptr, nullptr, nullptr, nullptr, flag,
      N_NODES, HID, OUT_DIM);
  // h4 = h3 @ W1 -> d_out tail (dual)
  gemm128<1><<<dim3(MB128, IN_DIM / 128), 256, 0, stream>>>(
      feat, nullptr, W1T, nullptr, d_out, (size_t)N_NODES * OUT_DIM,
      nullptr, nullptr, nullptr, nullptr, flag, N_NODES, IN_DIM, HID);
}